// Round 3
// baseline (2257.054 us; speedup 1.0000x reference)
//
#include <hip/hip_runtime.h>
#include <stdint.h>

typedef __bf16 bf16;
typedef __bf16 bf16x8 __attribute__((ext_vector_type(8)));
typedef float  f32x4  __attribute__((ext_vector_type(4)));

#define NB 16
// ---------------- ws layout (bytes) ----------------
// tagged h arrays: u32 {tag(hi16), h bf16(lo16)}, 128 slots x [blk16][b32][u16] = 32KB/slot
#define OFF_MF     0
#define OFF_MB     4096
#define OFF_H0F    8192
#define TAG_ONE    (128*32*256*4)                 // 4,194,304
#define OFF_H0B    (OFF_H0F + 1*TAG_ONE)
#define OFF_H1F    (OFF_H0F + 2*TAG_ONE)
#define OFF_H1B    (OFF_H0F + 3*TAG_ONE)
#define OFF_XF     (OFF_H0F + 4*TAG_ONE)          // 16,785,408
#define XF_BYTES   (4064*256*2)
#define OFF_XB     (OFF_XF + XF_BYTES)
#define OFF_FW0T   (OFF_XB + XF_BYTES)            // 20,946,944
#define W0T_BYTES  (1024*256*2)
#define OFF_BW0T   (OFF_FW0T + W0T_BYTES)
#define OFF_PRE0F  (OFF_BW0T + W0T_BYTES)         // 21,995,520
#define PRE_BYTES  (4064*1024*4)
#define OFF_PRE0B  (OFF_PRE0F + PRE_BYTES)        // end 55,287,808
// aliases (used only after recur; sources dead by then):
#define OFF_WPT    OFF_PRE0F                      // 32,768,000 <= 2*PRE
#define OFF_CTX    OFF_XF                         // 4,128,768 <= XF+XB

// system-scope (MALL-coherent, cache-bypassing) helpers
__device__ __forceinline__ uint64_t sys_load_u64(const uint64_t* p) {
  return __hip_atomic_load(p, __ATOMIC_RELAXED, __HIP_MEMORY_SCOPE_SYSTEM);
}
__device__ __forceinline__ void sys_store_u32(uint32_t* p, uint32_t v) {
  __hip_atomic_store(p, v, __ATOMIC_RELAXED, __HIP_MEMORY_SCOPE_SYSTEM);
}

// global->LDS direct staging (16B/lane)
typedef __attribute__((address_space(1))) unsigned int as1_u32;
typedef __attribute__((address_space(3))) unsigned int as3_u32;
__device__ __forceinline__ void gload16(const void* g, void* l) {
  __builtin_amdgcn_global_load_lds((as1_u32*)g, (as3_u32*)l, 16, 0, 0);
}

// ---- tagged-chunk helpers: one chunk = 4 k-steps = 4 octs = 16 u64 granules per lane ----
// granule address for (batch row b, oct o, dword-pair d): (o>>1)*256 + b*8 + (o&1)*4 + d
__device__ __forceinline__ void chunk_load(uint64_t g[4][4], const uint64_t* sb, int s0,
                                           int quad, int brow) {
  #pragma unroll
  for (int s = 0; s < 4; ++s)
    #pragma unroll
    for (int d = 0; d < 4; ++d) {
      int o = 4*(s0 + s) + quad;
      g[s][d] = sys_load_u64(sb + ((o >> 1)*256 + brow*8 + (o & 1)*4 + d));
    }
}
__device__ __forceinline__ bool chunk_ok(const uint64_t g[4][4], uint64_t want) {
  uint64_t x = 0;
  #pragma unroll
  for (int s = 0; s < 4; ++s)
    #pragma unroll
    for (int d = 0; d < 4; ++d) x |= (g[s][d] ^ want) & 0xFFFF0000FFFF0000ull;
  return x == 0;
}
__device__ __forceinline__ void chunk_wait(uint64_t g[4][4], const uint64_t* sb, int s0,
                                           int quad, int brow, uint64_t want) {
  int guard = 0;
  while (!chunk_ok(g, want)) {
    if (++guard > (1 << 18)) break;        // hang safety
    if (guard > 64) __builtin_amdgcn_s_sleep(1);
    chunk_load(g, sb, s0, quad, brow);
  }
}
// pack chunk granules to A-frags and run 4 MFMA against resident B-frags Bf[sbase..sbase+3]
__device__ __forceinline__ void chunk_mfma(const uint64_t g[4][4], const bf16x8* Bf,
                                           int sbase, f32x4& acc) {
  #pragma unroll
  for (int s = 0; s < 4; ++s) {
    union { uint32_t u[4]; bf16x8 v; } A;
    #pragma unroll
    for (int d = 0; d < 4; ++d) {
      uint64_t w = g[s][d];
      A.u[d] = (uint32_t)(w & 0xFFFFu) | ((uint32_t)((w >> 32) & 0xFFFFu) << 16);
    }
    acc = __builtin_amdgcn_mfma_f32_16x16x32_bf16(A.v, Bf[sbase + s], acc, 0, 0, 0);
  }
}

// ---------------- embedding gather + masks ----------------
__global__ __launch_bounds__(256) void embed_kernel(
    const int* __restrict__ x, const float* __restrict__ tab,
    bf16* __restrict__ xf, bf16* __restrict__ xb,
    unsigned char* __restrict__ mf, unsigned char* __restrict__ mb)
{
  int t = blockIdx.x;      // 0..126
  int b = blockIdx.y;      // 0..31
  int k = threadIdx.x;     // 0..255
  int tokf = x[b*128 + t];
  int tokb = x[b*128 + 127 - t];
  xf[(size_t)(t*32+b)*256 + k] = (bf16)tab[(size_t)tokf*256 + k];
  xb[(size_t)(t*32+b)*256 + k] = (bf16)tab[(size_t)tokb*256 + k];
  if (k == 0) { mf[t*32+b] = (tokf != 0); mb[t*32+b] = (tokb != 0); }
}

// ---------------- f32 [R][C] -> bf16 [C][R] transpose ----------------
__global__ __launch_bounds__(256) void transpose_to_bf16(
    const float* __restrict__ in, bf16* __restrict__ out, int R, int C)
{
  __shared__ float tile[64][65];
  int c0 = blockIdx.x*64, r0 = blockIdx.y*64;
  int tid = threadIdx.x;
  int r = tid >> 2, cs = (tid & 3)*16;
  #pragma unroll
  for (int i = 0; i < 16; i += 4) {
    float4 v = *(const float4*)(in + (size_t)(r0+r)*C + c0 + cs + i);
    tile[r][cs+i+0]=v.x; tile[r][cs+i+1]=v.y; tile[r][cs+i+2]=v.z; tile[r][cs+i+3]=v.w;
  }
  __syncthreads();
  int c = tid >> 2, rs = (tid & 3)*16;
  #pragma unroll
  for (int i = 0; i < 16; ++i)
    out[(size_t)(c0+c)*R + r0 + rs + i] = (bf16)tile[rs+i][c];
}

// ---------------- bf16 MFMA GEMM (m97-style global_load_lds staging) ----------------
__global__ __launch_bounds__(256) void gemm_bf16(
    const bf16* __restrict__ A, const bf16* __restrict__ BT,
    const float* __restrict__ bias, float* __restrict__ C,
    int M, int N, int K)
{
  __shared__ bf16 As[128][64];
  __shared__ bf16 Bs[128][64];
  int tid = threadIdx.x;
  int row0 = blockIdx.x*128, col0 = blockIdx.y*128;
  int wave = tid >> 6, lane = tid & 63, l15 = lane & 15, quad = lane >> 4;
  int wm = (wave & 1)*64, wn = (wave >> 1)*64;
  int lr = lane >> 3;
  int lc = (lane & 7)*8;
  f32x4 acc[4][4] = {};
  for (int kk = 0; kk < K; kk += 64) {
    #pragma unroll
    for (int i = 0; i < 4; ++i) {
      int rb = (wave*4 + i)*8;
      int ga = row0 + rb + lr; if (ga > M-1) ga = M-1;
      gload16(A  + (size_t)ga*K + kk + lc,                 &As[rb][0]);
      gload16(BT + (size_t)(col0 + rb + lr)*K + kk + lc,   &Bs[rb][0]);
    }
    __syncthreads();
    #pragma unroll
    for (int ks = 0; ks < 64; ks += 32) {
      bf16x8 af[4], bfr[4];
      #pragma unroll
      for (int mi = 0; mi < 4; ++mi) af[mi]  = *(const bf16x8*)&As[wm + mi*16 + l15][ks + quad*8];
      #pragma unroll
      for (int ni = 0; ni < 4; ++ni) bfr[ni] = *(const bf16x8*)&Bs[wn + ni*16 + l15][ks + quad*8];
      #pragma unroll
      for (int mi = 0; mi < 4; ++mi)
        #pragma unroll
        for (int ni = 0; ni < 4; ++ni)
          acc[mi][ni] = __builtin_amdgcn_mfma_f32_16x16x32_bf16(af[mi], bfr[ni], acc[mi][ni], 0, 0, 0);
    }
    __syncthreads();
  }
  #pragma unroll
  for (int ni = 0; ni < 4; ++ni) {
    int col = col0 + wn + ni*16 + l15;
    float bv = bias[col];
    #pragma unroll
    for (int mi = 0; mi < 4; ++mi) {
      int rbase = row0 + wm + mi*16 + quad*4;
      #pragma unroll
      for (int r = 0; r < 4; ++r) {
        int grow = rbase + r;
        if (grow < M) C[(size_t)grow*N + col] = acc[mi][ni][r] + bv;
      }
    }
  }
}

// ---------------- persistent LSTM recurrence — register-direct tagged handoff ----------------
// grid = 64 x 512: dir(2) x stage(2) x NB(16); block owns 16 units (64 z-cols).
// v3: weights live in registers (16 B-frags/wave = 64 VGPR); A-frags are built DIRECTLY from
// the tagged u64 loads (no hA LDS, no staging barrier). Per step the chain is:
//   tagged chunk loads (pipelined, 2 in flight) -> tag-check -> pack -> MFMA
//   -> z to z_s[parity] -> ONE barrier -> gates -> fire-and-forget tagged store.
// Each granule is read exactly once per block (octs partition across quads, m-halves disjoint).
// Stage1 checks h0 chunks (long-ready: stage0 runs ahead) before own-chain h1 chunks.
__global__ __launch_bounds__(512) void recur_kernel(
    const float* __restrict__ pre0f, const float* __restrict__ pre0b,
    const float* __restrict__ fU0, const float* __restrict__ bU0,
    const float* __restrict__ fW1, const float* __restrict__ fU1,
    const float* __restrict__ bW1, const float* __restrict__ bU1,
    const float* __restrict__ fb1, const float* __restrict__ bb1,
    const unsigned char* __restrict__ mf, const unsigned char* __restrict__ mb,
    uint32_t* __restrict__ h0f, uint32_t* __restrict__ h0b,
    uint32_t* __restrict__ h1f, uint32_t* __restrict__ h1b)
{
  __shared__ float z_s[2][32][65];   // parity double-buffered z (16.6 KB total LDS)

  int tid = threadIdx.x;
  int bx = blockIdx.x;
  int dir = bx >> 5, stage = (bx >> 4) & 1, blk = bx & 15;
  int j0 = blk * 16;
  const float* pre = dir ? pre0b : pre0f;
  const unsigned char* mgl = dir ? mb : mf;
  uint32_t* h0 = dir ? h0b : h0f;
  uint32_t* h1 = dir ? h1b : h1f;
  uint32_t* hout = stage ? h1 : h0;

  int wave = tid >> 6, lane = tid & 63, l15 = lane & 15, quad = lane >> 4;
  int m0 = (wave & 1)*16, n0 = (wave >> 1)*16;   // wave = (m-half, n-tile); 1 n-tile per wave
  int brow = m0 + l15;                            // batch row this lane's A covers
  int gc = (wave >> 1)*256 + j0 + l15;            // global gate-col this lane's B covers

  // ---- one-time: resident B fragments (weights), loaded straight from global ----
  // B-frag for k-step s: elements k = (4s+quad)*8 + e of column gc.
  bf16x8 Bf[16];
  if (stage == 0) {
    const float* U = dir ? bU0 : fU0;
    #pragma unroll
    for (int s = 0; s < 8; ++s) {
      bf16x8 f;
      #pragma unroll
      for (int e = 0; e < 8; ++e) f[e] = (bf16)U[(size_t)((4*s+quad)*8 + e)*1024 + gc];
      Bf[s] = f;
    }
  } else {
    const float* W = dir ? bW1 : fW1;
    const float* U = dir ? bU1 : fU1;
    #pragma unroll
    for (int s = 0; s < 16; ++s) {
      bf16x8 f;
      #pragma unroll
      for (int e = 0; e < 8; ++e) {
        int k = (4*s+quad)*8 + e;
        float v = (k < 256) ? W[(size_t)k*1024 + gc] : U[(size_t)(k-256)*1024 + gc];
        f[e] = (bf16)v;
      }
      Bf[s] = f;
    }
  }

  int gb = tid >> 4, gu = tid & 15;        // gate thread: batch gb, unit j0+gu (coalesced store)
  float c_state = 0.f, h_state = 0.f;
  float bi = 0.f, bff = 0.f, bgg = 0.f, boo = 0.f;
  if (stage == 1) {
    const float* bias = dir ? bb1 : fb1;
    bi  = bias[0*256 + j0 + gu];
    bff = bias[1*256 + j0 + gu];
    bgg = bias[2*256 + j0 + gu];
    boo = bias[3*256 + j0 + gu];
  }

  int par = 0;
  for (int t = 0; t < 127; ++t) {
    // step-constant operands — issue early, independent of handoff
    float p_i = bi, p_f = bff, p_g = bgg, p_o = boo;
    if (stage == 0) {
      const float* p = pre + ((size_t)t*32 + gb)*1024 + j0 + gu;
      p_i = p[0]; p_f = p[256]; p_g = p[512]; p_o = p[768];
    }
    unsigned char msk = mgl[t*32 + gb];

    f32x4 a0 = {0.f,0.f,0.f,0.f}, a1 = {0.f,0.f,0.f,0.f};
    uint64_t ga[4][4], gbuf[4][4];

    if (stage == 0) {
      if (t > 0) {
        const uint64_t* sp = (const uint64_t*)h0 + (size_t)t*4096;   // h0(t-1) @ slot t
        uint64_t want = ((uint64_t)t << 48) | ((uint64_t)t << 16);
        chunk_load(ga,   sp, 0, quad, brow);
        chunk_load(gbuf, sp, 4, quad, brow);
        chunk_wait(ga,   sp, 0, quad, brow, want);
        chunk_mfma(ga,   Bf, 0, a0);
        chunk_wait(gbuf, sp, 4, quad, brow, want);
        chunk_mfma(gbuf, Bf, 4, a1);
      }
    } else {
      const uint64_t* s0p = (const uint64_t*)h0 + (size_t)(t+1)*4096; // h0(t)   @ slot t+1
      const uint64_t* s1p = (const uint64_t*)h1 + (size_t)t*4096;     // h1(t-1) @ slot t
      uint64_t w0 = ((uint64_t)(t+1) << 48) | ((uint64_t)(t+1) << 16);
      uint64_t w1 = ((uint64_t)t << 48) | ((uint64_t)t << 16);
      chunk_load(ga,   s0p, 0, quad, brow);
      chunk_load(gbuf, s0p, 4, quad, brow);
      chunk_wait(ga,   s0p, 0, quad, brow, w0);
      chunk_mfma(ga,   Bf, 0, a0);
      if (t > 0) chunk_load(ga, s1p, 0, quad, brow);     // reuse ga regs for h1 chunk 2
      chunk_wait(gbuf, s0p, 4, quad, brow, w0);
      chunk_mfma(gbuf, Bf, 4, a0);
      if (t > 0) {
        chunk_load(gbuf, s1p, 4, quad, brow);            // h1 chunk 3
        chunk_wait(ga,   s1p, 0, quad, brow, w1);
        chunk_mfma(ga,   Bf, 8, a1);
        chunk_wait(gbuf, s1p, 4, quad, brow, w1);
        chunk_mfma(gbuf, Bf, 12, a1);
      }
    }

    // z to parity LDS buffer; ONE barrier per step
    f32x4 zac = a0 + a1;
    #pragma unroll
    for (int r = 0; r < 4; ++r) z_s[par][m0 + quad*4 + r][n0 + l15] = zac[r];
    __syncthreads();

    // gates (fp32, Keras i,f,g,o); lds col for (gate g, unit gu) = g*16+gu
    float zi = z_s[par][gb][ 0 + gu] + p_i;
    float zf = z_s[par][gb][16 + gu] + p_f;
    float zg = z_s[par][gb][32 + gu] + p_g;
    float zo = z_s[par][gb][48 + gu] + p_o;
    float ig = 1.f/(1.f + expf(-zi));
    float fg = 1.f/(1.f + expf(-zf));
    float gg = tanhf(zg);
    float og = 1.f/(1.f + expf(-zo));
    float cn = fg*c_state + ig*gg;
    float hn = og*tanhf(cn);
    if (msk) { c_state = cn; h_state = hn; }

    // fire-and-forget tagged store: {tag=t+1, h}; coalesced (index = blk*512 + tid)
    bf16 hv = (bf16)h_state;
    unsigned short hb;
    __builtin_memcpy(&hb, &hv, 2);
    uint32_t val = ((uint32_t)(t+1) << 16) | (uint32_t)hb;
    sys_store_u32(hout + (size_t)(t+1)*8192 + blk*512 + tid, val);
    par ^= 1;
  }
}

// ---------------- ctx assembly from tagged h1 (extract lo16) ----------------
// ctx[b*126+tau][0:256]=h1f(tau)@slot tau+1, [256:512]=h1b(tau+1)@slot tau+2
__global__ __launch_bounds__(256) void ctx_kernel(
    const uint32_t* __restrict__ h1f, const uint32_t* __restrict__ h1b, bf16* __restrict__ ctx)
{
  int tau = blockIdx.x;   // 0..125
  int b = blockIdx.y;     // 0..31
  int k = threadIdx.x;    // 0..255
  size_t r = (size_t)(b*126 + tau)*512;
  uint32_t vf = h1f[(size_t)(tau+1)*8192 + (k>>4)*512 + b*16 + (k&15)];
  uint32_t vb = h1b[(size_t)(tau+2)*8192 + (k>>4)*512 + b*16 + (k&15)];
  ((unsigned short*)ctx)[r + k]       = (unsigned short)(vf & 0xFFFF);
  ((unsigned short*)ctx)[r + 256 + k] = (unsigned short)(vb & 0xFFFF);
}

// ---------------- NSP head ----------------
__global__ __launch_bounds__(256) void nsp_kernel(
    const bf16* __restrict__ ctx, const float* __restrict__ Wn,
    const float* __restrict__ bn, float* __restrict__ out)
{
  int b = blockIdx.x, tid = threadIdx.x;
  const unsigned short* cb = (const unsigned short*)ctx;
  float a0 = 0.f, a1 = 0.f;
  for (int flat = tid; flat < 64512; flat += 256) {
    int tau = flat >> 9, k = flat & 511;
    float cv = __uint_as_float((unsigned)cb[(size_t)(b*126 + tau)*512 + k] << 16);
    float2 w = *(const float2*)(Wn + 2*(size_t)flat);
    a0 += cv*w.x; a1 += cv*w.y;
  }
  __shared__ float r0[256], r1[256];
  r0[tid] = a0; r1[tid] = a1;
  __syncthreads();
  for (int s = 128; s > 0; s >>= 1) {
    if (tid < s) { r0[tid] += r0[tid+s]; r1[tid] += r1[tid+s]; }
    __syncthreads();
  }
  if (tid == 0) { out[b*2+0] = r0[0] + bn[0]; out[b*2+1] = r1[0] + bn[1]; }
}

// ---------------- launch ----------------
extern "C" void kernel_launch(void* const* d_in, const int* in_sizes, int n_in,
                              void* d_out, int out_size, void* d_ws, size_t ws_size,
                              hipStream_t stream)
{
  const int*   x   = (const int*)d_in[0];
  const float* tab = (const float*)d_in[1];
  const float* fW  = (const float*)d_in[2];
  const float* fU  = (const float*)d_in[3];
  const float* fb  = (const float*)d_in[4];
  const float* bW  = (const float*)d_in[5];
  const float* bU  = (const float*)d_in[6];
  const float* bb  = (const float*)d_in[7];
  const float* Wp  = (const float*)d_in[8];
  const float* bp  = (const float*)d_in[9];
  const float* Wn  = (const float*)d_in[10];
  const float* bn  = (const float*)d_in[11];
  float* out = (float*)d_out;
  char* ws = (char*)d_ws;

  unsigned char* mf = (unsigned char*)(ws + OFF_MF);
  unsigned char* mb = (unsigned char*)(ws + OFF_MB);
  uint32_t* h0f = (uint32_t*)(ws + OFF_H0F);
  uint32_t* h0b = (uint32_t*)(ws + OFF_H0B);
  uint32_t* h1f = (uint32_t*)(ws + OFF_H1F);
  uint32_t* h1b = (uint32_t*)(ws + OFF_H1B);
  bf16* xf    = (bf16*)(ws + OFF_XF);
  bf16* xb    = (bf16*)(ws + OFF_XB);
  bf16* fW0T  = (bf16*)(ws + OFF_FW0T);
  bf16* bW0T  = (bf16*)(ws + OFF_BW0T);
  float* pre0f = (float*)(ws + OFF_PRE0F);
  float* pre0b = (float*)(ws + OFF_PRE0B);
  bf16* WpT   = (bf16*)(ws + OFF_WPT);   // aliases pre0f/pre0b (dead after recur)
  bf16* ctx   = (bf16*)(ws + OFF_CTX);   // aliases xf/xb (dead after pre-GEMMs)

  // zero tags in all four tagged h arrays (tag 0 = invalid; slot 0 never read as valid)
  hipMemsetAsync(ws + OFF_H0F, 0, 4*(size_t)TAG_ONE, stream);

  embed_kernel<<<dim3(127, 32), 256, 0, stream>>>(x, tab, xf, xb, mf, mb);

  transpose_to_bf16<<<dim3(16, 4),  256, 0, stream>>>(fW, fW0T, 256, 1024);
  transpose_to_bf16<<<dim3(16, 4),  256, 0, stream>>>(bW, bW0T, 256, 1024);

  gemm_bf16<<<dim3(32, 8), 256, 0, stream>>>(xf, fW0T, fb, pre0f, 4064, 1024, 256);
  gemm_bf16<<<dim3(32, 8), 256, 0, stream>>>(xb, bW0T, bb, pre0b, 4064, 1024, 256);

  recur_kernel<<<64, 512, 0, stream>>>(
      pre0f, pre0b,
      fU, bU,
      fW + 262144, fU + 262144, bW + 262144, bU + 262144,
      fb + 1024, bb + 1024,
      mf, mb, h0f, h0b, h1f, h1b);

  // Wp transpose AFTER recur: WPT aliases the pre buffers
  transpose_to_bf16<<<dim3(500, 8), 256, 0, stream>>>(Wp, WpT, 512, 32000);

  ctx_kernel<<<dim3(126, 32), 256, 0, stream>>>(h1f, h1b, ctx);

  gemm_bf16<<<dim3(32, 250), 256, 0, stream>>>(ctx, WpT, bp, out, 4032, 32000, 512);

  nsp_kernel<<<32, 256, 0, stream>>>(ctx, Wn, bn, out + (size_t)4032*32000);
}